// Round 1
// baseline (71.986 us; speedup 1.0000x reference)
//
#include <hip/hip_runtime.h>

typedef __bf16 bf16_t;
typedef bf16_t bf16x4 __attribute__((ext_vector_type(4)));
typedef bf16_t bf16x8 __attribute__((ext_vector_type(8)));
typedef float f32x4 __attribute__((ext_vector_type(4)));

#define INFV 10000.0f

// ---------------- kernel 0: w1 (1024x128 f32) -> w1T (128x1024 bf16) ----------------
__global__ __launch_bounds__(256) void k0_transpose(const float* __restrict__ w1,
                                                    bf16_t* __restrict__ w1T) {
    __shared__ float s[32][36];
    const int t = threadIdx.x;
    const int k0 = (blockIdx.x & 31) * 32;  // 1024/32
    const int c0 = (blockIdx.x >> 5) * 32;  // 128/32
    {
        const int r = t >> 3, cc = (t & 7) * 4;
        *(float4*)&s[r][cc] = *(const float4*)&w1[(size_t)(k0 + r) * 128 + c0 + cc];
    }
    __syncthreads();
    {
        const int cr = t >> 3, kk = (t & 7) * 4;
        bf16x4 v;
        v[0] = (bf16_t)s[kk + 0][cr];
        v[1] = (bf16_t)s[kk + 1][cr];
        v[2] = (bf16_t)s[kk + 2][cr];
        v[3] = (bf16_t)s[kk + 3][cr];
        *(bf16x4*)&w1T[(size_t)(c0 + cr) * 1024 + k0 + kk] = v;
    }
}

// ---------------- kernel 1: x = inputs@w1 + b1 ; rope -> q,k (bf16) ; biasT = ((x@w2+b2)/2)^T
__global__ __launch_bounds__(256) void k1_proj(
    const float* __restrict__ inputs,   // [8192][1024]
    const bf16_t* __restrict__ w1T,     // [128][1024] bf16
    const float* __restrict__ b1,       // [128]
    const float* __restrict__ w2,       // [128][24]
    const float* __restrict__ b2,       // [24]
    bf16_t* __restrict__ qg,            // [8192][64] bf16
    bf16_t* __restrict__ kg,            // [8192][64] bf16
    float* __restrict__ biasT)          // [16][24][512]
{
    __shared__ bf16_t s_a[32][72];      // 32 rows x 64 k (pad 8)
    __shared__ float s_x[32][132];
    __shared__ float s_w2T[24][132];

    const int t = threadIdx.x;
    const int row0 = blockIdx.x * 32;
    const int lane = t & 63, wave = t >> 6;
    const int wm = wave >> 1, wn = wave & 1;
    const int cn = lane & 15, kgrp = lane >> 4;

    // stage w2 transposed (read much later, after many barriers)
    for (int i = t; i < 3072; i += 256) {
        int j = i / 24, c = i - j * 24;
        s_w2T[c][j] = w2[i];
    }

    f32x4 acc[4] = {};
    const int sr0 = t >> 4, sc0 = (t & 15) * 4;
    const int sr1 = 16 + sr0;
    float4 pf0 = *(const float4*)&inputs[(size_t)(row0 + sr0) * 1024 + sc0];
    float4 pf1 = *(const float4*)&inputs[(size_t)(row0 + sr1) * 1024 + sc0];

    for (int ks = 0; ks < 16; ++ks) {
        const int k0 = ks * 64;
        {
            bf16x4 v0, v1;
            v0[0] = (bf16_t)pf0.x; v0[1] = (bf16_t)pf0.y; v0[2] = (bf16_t)pf0.z; v0[3] = (bf16_t)pf0.w;
            v1[0] = (bf16_t)pf1.x; v1[1] = (bf16_t)pf1.y; v1[2] = (bf16_t)pf1.z; v1[3] = (bf16_t)pf1.w;
            *(bf16x4*)&s_a[sr0][sc0] = v0;
            *(bf16x4*)&s_a[sr1][sc0] = v1;
        }
        __syncthreads();
        if (ks < 15) {
            pf0 = *(const float4*)&inputs[(size_t)(row0 + sr0) * 1024 + k0 + 64 + sc0];
            pf1 = *(const float4*)&inputs[(size_t)(row0 + sr1) * 1024 + k0 + 64 + sc0];
        }
        const int arow = wm * 16 + cn;
        bf16x8 a0 = *(const bf16x8*)&s_a[arow][kgrp * 8];
        bf16x8 a1 = *(const bf16x8*)&s_a[arow][32 + kgrp * 8];
#pragma unroll
        for (int tt = 0; tt < 4; ++tt) {
            const int col = wn * 64 + tt * 16 + cn;
            const bf16_t* wp = w1T + (size_t)col * 1024 + k0 + kgrp * 8;
            bf16x8 bb0 = *(const bf16x8*)wp;
            bf16x8 bb1 = *(const bf16x8*)(wp + 32);
            acc[tt] = __builtin_amdgcn_mfma_f32_16x16x32_bf16(a0, bb0, acc[tt], 0, 0, 0);
            acc[tt] = __builtin_amdgcn_mfma_f32_16x16x32_bf16(a1, bb1, acc[tt], 0, 0, 0);
        }
        __syncthreads();
    }

    // epilogue: x tile (+b1) to LDS
    {
        const int rgrp = lane >> 4;
#pragma unroll
        for (int tt = 0; tt < 4; ++tt) {
            const int col = wn * 64 + tt * 16 + cn;
            const float bb = b1[col];
#pragma unroll
            for (int r = 0; r < 4; ++r)
                s_x[wm * 16 + rgrp * 4 + r][col] = acc[tt][r] + bb;
        }
    }
    __syncthreads();

    // rope -> qg, kg (bf16)
    {
        const int r = t >> 3;
        const int i0 = (t & 7) * 4;
        const int rowg = row0 + r;
        const int n = rowg & 511;
        bf16x8 qv, kv;
#pragma unroll
        for (int u = 0; u < 4; ++u) {
            const int i = i0 + u;
            // inv_freq = 10000^(-i/32) = exp2(-i * log2(10000)/32)
            float fr = (float)n * exp2f((float)i * -0.4152410118609203f);
            float sv, cv;
            sincosf(fr, &sv, &cv);
            float x0 = s_x[r][4 * i + 0];
            float x1 = s_x[r][4 * i + 1];
            float x2 = s_x[r][4 * i + 2];
            float x3 = s_x[r][4 * i + 3];
            qv[2 * u]     = (bf16_t)(x0 * cv - x2 * sv);
            qv[2 * u + 1] = (bf16_t)(x0 * sv + x2 * cv);
            kv[2 * u]     = (bf16_t)(x1 * cv - x3 * sv);
            kv[2 * u + 1] = (bf16_t)(x1 * sv + x3 * cv);
        }
        *(bf16x8*)&qg[(size_t)rowg * 64 + 2 * i0] = qv;
        *(bf16x8*)&kg[(size_t)rowg * 64 + 2 * i0] = kv;
    }

    // bias: (x @ w2 + b2) * 0.5 -> biasT[b][c][n]
    {
        const int r = t >> 3;
        const int cb = (t & 7) * 3;
        float sum0 = 0.f, sum1 = 0.f, sum2 = 0.f;
#pragma unroll 4
        for (int j = 0; j < 128; j += 4) {
            float4 xv = *(const float4*)&s_x[r][j];
            float4 wa = *(const float4*)&s_w2T[cb + 0][j];
            float4 wb = *(const float4*)&s_w2T[cb + 1][j];
            float4 wc = *(const float4*)&s_w2T[cb + 2][j];
            sum0 += xv.x * wa.x + xv.y * wa.y + xv.z * wa.z + xv.w * wa.w;
            sum1 += xv.x * wb.x + xv.y * wb.y + xv.z * wb.z + xv.w * wb.w;
            sum2 += xv.x * wc.x + xv.y * wc.y + xv.z * wc.z + xv.w * wc.w;
        }
        const int rowg = row0 + r;
        const int bb = rowg >> 9, n = rowg & 511;
        float* bp = biasT + (size_t)bb * 12288 + n;
        bp[(size_t)(cb + 0) * 512] = (sum0 + b2[cb + 0]) * 0.5f;
        bp[(size_t)(cb + 1) * 512] = (sum1 + b2[cb + 1]) * 0.5f;
        bp[(size_t)(cb + 2) * 512] = (sum2 + b2[cb + 2]) * 0.5f;
    }
}

// ---------------- kernel 2: logits[b,h,m,n] = qk/8 + bE[h][n] + bO[h][m] - masks ----------------
__global__ __launch_bounds__(256) void k2_logits(
    const bf16_t* __restrict__ qg, const bf16_t* __restrict__ kg,
    const float* __restrict__ biasT, const int* __restrict__ am,
    float* __restrict__ out)
{
    __shared__ float s_be[12][64], s_bo[12][64];
    __shared__ float s_pm[64], s_pn[64];

    const int t = threadIdx.x;
    const int b = blockIdx.z;
    const int m0 = blockIdx.y * 64;
    const int n0 = blockIdx.x * 64;

    for (int i = t; i < 768; i += 256) {
        const int h = i >> 6, j = i & 63;
        s_be[h][j] = biasT[(size_t)b * 12288 + (size_t)(2 * h) * 512 + n0 + j];
        s_bo[h][j] = biasT[(size_t)b * 12288 + (size_t)(2 * h + 1) * 512 + m0 + j];
    }
    if (t < 64) s_pm[t] = (float)am[b * 512 + m0 + t];
    else if (t < 128) s_pn[t - 64] = (float)am[b * 512 + n0 + (t - 64)];

    const int lane = t & 63, wave = t >> 6;
    const int cn = lane & 15, kgrp = lane >> 4;

    // A-frag: q rows (m), direct from global (coalesced 16B/lane, L2-hit)
    const bf16_t* qp = qg + ((size_t)(b * 512 + m0 + wave * 16 + cn)) * 64 + kgrp * 8;
    bf16x8 a0 = *(const bf16x8*)qp;
    bf16x8 a1 = *(const bf16x8*)(qp + 32);

    f32x4 acc[4] = {};
#pragma unroll
    for (int nt = 0; nt < 4; ++nt) {
        const bf16_t* kp = kg + ((size_t)(b * 512 + n0 + nt * 16 + cn)) * 64 + kgrp * 8;
        bf16x8 bb0 = *(const bf16x8*)kp;
        bf16x8 bb1 = *(const bf16x8*)(kp + 32);
        acc[nt] = __builtin_amdgcn_mfma_f32_16x16x32_bf16(a0, bb0, acc[nt], 0, 0, 0);
        acc[nt] = __builtin_amdgcn_mfma_f32_16x16x32_bf16(a1, bb1, acc[nt], 0, 0, 0);
    }
    __syncthreads();

    const int rgrp = lane >> 4;
    // fold scale + pad mask + causal mask (h-independent)
#pragma unroll
    for (int nt = 0; nt < 4; ++nt) {
        const int n = nt * 16 + cn;
        const float an = s_pn[n];
#pragma unroll
        for (int rg = 0; rg < 4; ++rg) {
            const int m = wave * 16 + rgrp * 4 + rg;
            float v = acc[nt][rg] * 0.125f;
            v -= (1.0f - s_pm[m] * an) * INFV;
            if (m0 + m > n0 + n) v -= INFV;
            acc[nt][rg] = v;
        }
    }

    float* ob = out + (size_t)b * 3145728 + (size_t)m0 * 512 + n0;
    for (int h = 0; h < 12; ++h) {
#pragma unroll
        for (int nt = 0; nt < 4; ++nt) {
            const int n = nt * 16 + cn;
            const float be = s_be[h][n];
#pragma unroll
            for (int rg = 0; rg < 4; ++rg) {
                const int m = wave * 16 + rgrp * 4 + rg;
                ob[(size_t)h * 262144 + (size_t)m * 512 + n] = acc[nt][rg] + be + s_bo[h][m];
            }
        }
    }
}

extern "C" void kernel_launch(void* const* d_in, const int* in_sizes, int n_in,
                              void* d_out, int out_size, void* d_ws, size_t ws_size,
                              hipStream_t stream) {
    const float* inputs = (const float*)d_in[0];
    const int*   am     = (const int*)d_in[1];
    const float* w1     = (const float*)d_in[2];
    const float* b1     = (const float*)d_in[3];
    const float* w2     = (const float*)d_in[4];
    const float* b2     = (const float*)d_in[5];
    float* out = (float*)d_out;

    bf16_t* w1T   = (bf16_t*)d_ws;           // 128*1024 bf16   = 256 KB
    bf16_t* qg    = w1T + 131072;            // 8192*64 bf16    = 1 MB
    bf16_t* kg    = qg + 524288;             // 8192*64 bf16    = 1 MB
    float*  biasT = (float*)(kg + 524288);   // 16*24*512 f32   = 768 KB

    k0_transpose<<<128, 256, 0, stream>>>(w1, w1T);
    k1_proj<<<256, 256, 0, stream>>>(inputs, w1T, b1, w2, b2, qg, kg, biasT);
    k2_logits<<<dim3(8, 8, 16), 256, 0, stream>>>(qg, kg, biasT, am, out);
}

// Round 2
// 67.710 us; speedup vs baseline: 1.0632x; 1.0632x over previous
//
#include <hip/hip_runtime.h>

typedef __bf16 bf16_t;
typedef bf16_t bf16x4 __attribute__((ext_vector_type(4)));
typedef bf16_t bf16x8 __attribute__((ext_vector_type(8)));
typedef float f32x4 __attribute__((ext_vector_type(4)));

#define INFV 10000.0f

// ---------------- kernel 0: w1 (1024x128 f32) -> w1T (128x1024 bf16) ----------------
__global__ __launch_bounds__(256) void k0_transpose(const float* __restrict__ w1,
                                                    bf16_t* __restrict__ w1T) {
    __shared__ float s[32][36];
    const int t = threadIdx.x;
    const int k0 = (blockIdx.x & 31) * 32;  // 1024/32
    const int c0 = (blockIdx.x >> 5) * 32;  // 128/32
    {
        const int r = t >> 3, cc = (t & 7) * 4;
        *(float4*)&s[r][cc] = *(const float4*)&w1[(size_t)(k0 + r) * 128 + c0 + cc];
    }
    __syncthreads();
    {
        const int cr = t >> 3, kk = (t & 7) * 4;
        bf16x4 v;
        v[0] = (bf16_t)s[kk + 0][cr];
        v[1] = (bf16_t)s[kk + 1][cr];
        v[2] = (bf16_t)s[kk + 2][cr];
        v[3] = (bf16_t)s[kk + 3][cr];
        *(bf16x4*)&w1T[(size_t)(c0 + cr) * 1024 + k0 + kk] = v;
    }
}

// ---------------- kernel 1: x = inputs@w1 + b1 ; rope -> q,k (bf16) ; biasT = ((x@w2+b2)/2)^T
// 512 blocks x 16 rows each -> 2 blocks/CU, 8 waves/CU (latency hiding).
__global__ __launch_bounds__(256) void k1_proj(
    const float* __restrict__ inputs,   // [8192][1024]
    const bf16_t* __restrict__ w1T,     // [128][1024] bf16
    const float* __restrict__ b1,       // [128]
    const float* __restrict__ w2,       // [128][24]
    const float* __restrict__ b2,       // [24]
    bf16_t* __restrict__ qg,            // [8192][64] bf16
    bf16_t* __restrict__ kg,            // [8192][64] bf16
    float* __restrict__ biasT)          // [16][24][512]
{
    __shared__ bf16_t s_a[16][72];      // 16 rows x 64 k (pad 8)
    __shared__ float s_x[16][132];
    __shared__ float s_w2T[24][132];

    const int t = threadIdx.x;
    const int row0 = blockIdx.x * 16;
    const int lane = t & 63, wave = t >> 6;
    const int cn = lane & 15, kgrp = lane >> 4;

    // stage w2 transposed (consumed after the K-loop's barriers)
    for (int i = t; i < 3072; i += 256) {
        int j = i / 24, c = i - j * 24;
        s_w2T[c][j] = w2[i];
    }

    f32x4 acc[2] = {};
    const int sr = t >> 4;          // 0..15
    const int sc = (t & 15) * 4;    // 0..60
    float4 pf = *(const float4*)&inputs[(size_t)(row0 + sr) * 1024 + sc];

    for (int ks = 0; ks < 16; ++ks) {
        const int k0 = ks * 64;
        {
            bf16x4 v;
            v[0] = (bf16_t)pf.x; v[1] = (bf16_t)pf.y; v[2] = (bf16_t)pf.z; v[3] = (bf16_t)pf.w;
            *(bf16x4*)&s_a[sr][sc] = v;
        }
        __syncthreads();
        if (ks < 15)
            pf = *(const float4*)&inputs[(size_t)(row0 + sr) * 1024 + k0 + 64 + sc];
        bf16x8 a0 = *(const bf16x8*)&s_a[cn][kgrp * 8];
        bf16x8 a1 = *(const bf16x8*)&s_a[cn][32 + kgrp * 8];
#pragma unroll
        for (int tt = 0; tt < 2; ++tt) {
            const int col = wave * 32 + tt * 16 + cn;
            const bf16_t* wp = w1T + (size_t)col * 1024 + k0 + kgrp * 8;
            bf16x8 bb0 = *(const bf16x8*)wp;
            bf16x8 bb1 = *(const bf16x8*)(wp + 32);
            acc[tt] = __builtin_amdgcn_mfma_f32_16x16x32_bf16(a0, bb0, acc[tt], 0, 0, 0);
            acc[tt] = __builtin_amdgcn_mfma_f32_16x16x32_bf16(a1, bb1, acc[tt], 0, 0, 0);
        }
        __syncthreads();
    }

    // epilogue: x tile (+b1) to LDS. D-layout: row = (lane>>4)*4+reg, col = lane&15
    {
        const int rgrp = lane >> 4;
#pragma unroll
        for (int tt = 0; tt < 2; ++tt) {
            const int col = wave * 32 + tt * 16 + cn;
            const float bb = b1[col];
#pragma unroll
            for (int r = 0; r < 4; ++r)
                s_x[rgrp * 4 + r][col] = acc[tt][r] + bb;
        }
    }
    __syncthreads();

    // rope -> qg, kg (bf16): 16 threads/row, 2 freq-indices each
    {
        const int r = t >> 4;
        const int i0 = (t & 15) * 2;
        const int rowg = row0 + r;
        const int n = rowg & 511;
        bf16x4 qv, kv;
#pragma unroll
        for (int u = 0; u < 2; ++u) {
            const int i = i0 + u;
            // inv_freq = 10000^(-i/32) = exp2(-i * log2(10000)/32)
            float fr = (float)n * exp2f((float)i * -0.4152410118609203f);
            float sv, cv;
            sincosf(fr, &sv, &cv);
            float x0 = s_x[r][4 * i + 0];
            float x1 = s_x[r][4 * i + 1];
            float x2 = s_x[r][4 * i + 2];
            float x3 = s_x[r][4 * i + 3];
            qv[2 * u]     = (bf16_t)(x0 * cv - x2 * sv);
            qv[2 * u + 1] = (bf16_t)(x0 * sv + x2 * cv);
            kv[2 * u]     = (bf16_t)(x1 * cv - x3 * sv);
            kv[2 * u + 1] = (bf16_t)(x1 * sv + x3 * cv);
        }
        *(bf16x4*)&qg[(size_t)rowg * 64 + 2 * i0] = qv;
        *(bf16x4*)&kg[(size_t)rowg * 64 + 2 * i0] = kv;
    }

    // bias: (x @ w2 + b2) * 0.5 -> biasT[b][c][n]; 12 threads/row x 2 cols
    {
        const int r = t >> 4;
        const int cb = t & 15;
        if (cb < 12) {
            const int c0 = cb * 2;
            float sum0 = 0.f, sum1 = 0.f;
#pragma unroll 4
            for (int j = 0; j < 128; j += 4) {
                float4 xv = *(const float4*)&s_x[r][j];
                float4 wa = *(const float4*)&s_w2T[c0 + 0][j];
                float4 wb = *(const float4*)&s_w2T[c0 + 1][j];
                sum0 += xv.x * wa.x + xv.y * wa.y + xv.z * wa.z + xv.w * wa.w;
                sum1 += xv.x * wb.x + xv.y * wb.y + xv.z * wb.z + xv.w * wb.w;
            }
            const int rowg = row0 + r;
            const int bb = rowg >> 9, n = rowg & 511;
            float* bp = biasT + (size_t)bb * 12288 + n;
            bp[(size_t)(c0 + 0) * 512] = (sum0 + b2[c0 + 0]) * 0.5f;
            bp[(size_t)(c0 + 1) * 512] = (sum1 + b2[c0 + 1]) * 0.5f;
        }
    }
}

// ---------------- kernel 2: logits[b,h,m,n] = qk/8 + bE[h][n] + bO[h][m] - masks ----------------
// Swapped MFMA operands: D[n][m] = mfma(K_frag, Q_frag) so each lane holds 4
// consecutive n -> float4 stores along n (48 dwordx4/thread vs 192 scalars).
__global__ __launch_bounds__(256) void k2_logits(
    const bf16_t* __restrict__ qg, const bf16_t* __restrict__ kg,
    const float* __restrict__ biasT, const int* __restrict__ am,
    float* __restrict__ out)
{
    __shared__ float s_be[12][64], s_bo[12][64];
    __shared__ float s_pm[64], s_pn[64];

    const int t = threadIdx.x;
    const int b = blockIdx.z;
    const int m0 = blockIdx.y * 64;
    const int n0 = blockIdx.x * 64;

    for (int i = t; i < 768; i += 256) {
        const int h = i >> 6, j = i & 63;
        s_be[h][j] = biasT[(size_t)b * 12288 + (size_t)(2 * h) * 512 + n0 + j];
        s_bo[h][j] = biasT[(size_t)b * 12288 + (size_t)(2 * h + 1) * 512 + m0 + j];
    }
    if (t < 64) s_pm[t] = (float)am[b * 512 + m0 + t];
    else if (t < 128) s_pn[t - 64] = (float)am[b * 512 + n0 + (t - 64)];

    const int lane = t & 63, wave = t >> 6;
    const int cn = lane & 15, kgrp = lane >> 4;

    // B-frag: q rows (m), fixed per wave; direct from global (L2-hit)
    const bf16_t* qp = qg + ((size_t)(b * 512 + m0 + wave * 16 + cn)) * 64 + kgrp * 8;
    bf16x8 qb0 = *(const bf16x8*)qp;
    bf16x8 qb1 = *(const bf16x8*)(qp + 32);

    f32x4 acc[4] = {};
#pragma unroll
    for (int nt = 0; nt < 4; ++nt) {
        const bf16_t* kp = kg + ((size_t)(b * 512 + n0 + nt * 16 + cn)) * 64 + kgrp * 8;
        bf16x8 ka0 = *(const bf16x8*)kp;
        bf16x8 ka1 = *(const bf16x8*)(kp + 32);
        acc[nt] = __builtin_amdgcn_mfma_f32_16x16x32_bf16(ka0, qb0, acc[nt], 0, 0, 0);
        acc[nt] = __builtin_amdgcn_mfma_f32_16x16x32_bf16(ka1, qb1, acc[nt], 0, 0, 0);
    }
    __syncthreads();

    const int rgrp = lane >> 4;
    const int m_loc = wave * 16 + cn;       // this thread's (fixed) m
    const int m = m0 + m_loc;
    const float am_m = s_pm[m_loc];

    // fold scale + pad mask + causal mask (h-independent)
#pragma unroll
    for (int nt = 0; nt < 4; ++nt) {
#pragma unroll
        for (int r = 0; r < 4; ++r) {
            const int n_loc = nt * 16 + rgrp * 4 + r;
            float v = acc[nt][r] * 0.125f;
            v -= (1.0f - am_m * s_pn[n_loc]) * INFV;
            if (m > n0 + n_loc) v -= INFV;
            acc[nt][r] = v;
        }
    }

    float* ob = out + (size_t)b * 3145728 + (size_t)m * 512 + n0;
#pragma unroll
    for (int h = 0; h < 12; ++h) {
        const float bo = s_bo[h][m_loc];
        const f32x4 bov = {bo, bo, bo, bo};
#pragma unroll
        for (int nt = 0; nt < 4; ++nt) {
            const f32x4 be4 = *(const f32x4*)&s_be[h][nt * 16 + rgrp * 4];
            f32x4 w = acc[nt] + be4 + bov;
            *(f32x4*)&ob[(size_t)h * 262144 + nt * 16 + rgrp * 4] = w;
        }
    }
}

extern "C" void kernel_launch(void* const* d_in, const int* in_sizes, int n_in,
                              void* d_out, int out_size, void* d_ws, size_t ws_size,
                              hipStream_t stream) {
    const float* inputs = (const float*)d_in[0];
    const int*   am     = (const int*)d_in[1];
    const float* w1     = (const float*)d_in[2];
    const float* b1     = (const float*)d_in[3];
    const float* w2     = (const float*)d_in[4];
    const float* b2     = (const float*)d_in[5];
    float* out = (float*)d_out;

    bf16_t* w1T   = (bf16_t*)d_ws;           // 128*1024 bf16   = 256 KB
    bf16_t* qg    = w1T + 131072;            // 8192*64 bf16    = 1 MB
    bf16_t* kg    = qg + 524288;             // 8192*64 bf16    = 1 MB
    float*  biasT = (float*)(kg + 524288);   // 16*24*512 f32   = 768 KB

    k0_transpose<<<128, 256, 0, stream>>>(w1, w1T);
    k1_proj<<<512, 256, 0, stream>>>(inputs, w1T, b1, w2, b2, qg, kg, biasT);
    k2_logits<<<dim3(8, 8, 16), 256, 0, stream>>>(qg, kg, biasT, am, out);
}